// Round 16
// baseline (1627.902 us; speedup 1.0000x reference)
//
#include <hip/hip_runtime.h>

#define L_SEQ 2048
#define C_IN  64
#define HH    128
#define NSEQ  32
#define G3    384
#define XW32  (C_IN / 2)                 // 32 u32 per packed x row
#define XTOT  (NSEQ * L_SEQ * XW32)
#define RSLOT 32                         // ring slots per sequence (2 windows)
#define RCOL  3                          // 3 gates adjacent per col

typedef _Float16 f16x8 __attribute__((ext_vector_type(8)));
typedef float    f32x4 __attribute__((ext_vector_type(4)));
typedef _Float16 half2_t __attribute__((ext_vector_type(2)));

#define PINU(v) asm volatile("" : "+v"(v))
// per-step barrier: drain LDS only; vmcnt (out stores, x loads) floats
#define STEP_BARRIER() asm volatile("s_waitcnt lgkmcnt(0)\n\ts_barrier" ::: "memory")
#define MFMA16(a, b, c) __builtin_amdgcn_mfma_f32_16x16x32_f16((a), (b), (c), 0, 0, 0)

__device__ __forceinline__ float fdot2u(unsigned int a, unsigned int b, float c) {
    return __builtin_amdgcn_fdot2(__builtin_bit_cast(half2_t, a),
                                  __builtin_bit_cast(half2_t, b), c, false);
}
__device__ __forceinline__ unsigned int pack_h2(float a, float b) {
    half2_t t; t.x = (_Float16)a; t.y = (_Float16)b;
    return __builtin_bit_cast(unsigned int, t);
}
__device__ __forceinline__ float qadd1(float x) {     // += lane^1 (DPP, no DS)
    int t = __builtin_amdgcn_update_dpp(0, __builtin_bit_cast(int, x),
                                        0xB1, 0xF, 0xF, true);
    return x + __builtin_bit_cast(float, t);
}
__device__ __forceinline__ float fast_sigmoid(float x) {
    float e = __builtin_amdgcn_exp2f(-1.4426950408889634f * x);
    return __builtin_amdgcn_rcpf(1.0f + e);
}
__device__ __forceinline__ float fast_tanh(float x) {
    float a = fabsf(x);
    float e = __builtin_amdgcn_exp2f(-2.8853900817779268f * a);
    float r = (1.0f - e) * __builtin_amdgcn_rcpf(1.0f + e);
    return copysignf(r, x);
}

// ---------------------------------------------------------------------------
__global__ __launch_bounds__(256)
void pack_x_kernel(const float* __restrict__ x, unsigned int* __restrict__ xh)
{
    const size_t i = (size_t)blockIdx.x * 256 + threadIdx.x;
    if (i < (size_t)XTOT) {
        const float2 v = ((const float2*)x)[i];
        xh[i] = pack_h2(v.x, v.y);
    }
    if (i < XW32) xh[(size_t)XTOT + i] = 0u;     // zero row for ragged tail
}

// ---------------------------------------------------------------------------
// Dual-sequence fused BiGRU: 32 blocks x 256 threads; block b runs fwd(b) AND
// rev(b) in the SAME threads (two independent dep chains per thread -> chain
// A's stall cycles absorb chain B's issue; W_hh registers shared by both).
// Recurrence: thread = (col j = tid>>1, K-half p = tid&1); 96 pinned packed
//   f16-pair W_hh u32; 96 dot2 per seq per step; one DPP qadd1 per gate;
//   h f16 double-buffered in LDS (per seq).
// X-projection (matrix pipe): every 16 steps per seq (staggered t%16==0 fwd,
//   ==8 rev) one M=16 MFMA batch (12 MFMA) fills ring window [t+16,t+32)
//   (fwd) / [t+8,t+24) (rev). Ring [seq][32][128cols][3gates] -> one b96
//   read per seq per step (3j mod 32: conflict-free). 96 KB LDS, 1 blk/CU.
// One lgkm-only barrier per step.
// ---------------------------------------------------------------------------
__global__ __launch_bounds__(256) __attribute__((amdgpu_waves_per_eu(1, 1)))
void bigru_dual(const unsigned int* __restrict__ xh,
                const int* __restrict__ lengths,
                const float* __restrict__ W_ih, const float* __restrict__ W_hh,
                const float* __restrict__ b_ih, const float* __restrict__ b_hh,
                float* __restrict__ out)
{
    __shared__ float ring[2][RSLOT][HH * RCOL];  // 96 KB
    __shared__ unsigned int hbufu[2][2][64];     // [seq][buf][col-pair]

    const int tid = threadIdx.x;
    const int b   = blockIdx.x;                  // batch element 0..31
    const int j   = tid >> 1;                    // col 0..127
    const int p   = tid & 1;                     // K half
    const int w   = tid >> 6;                    // wave -> gate cols [32w,32w+32)
    const int l   = tid & 63;
    const int lm  = l & 15;
    const int lg  = l >> 4;

    // ---- shared recurrence weights (both chains), pinned ----
    unsigned int wr[32], wz[32], wn[32];
    {
        const float* Wb = W_hh + (size_t)(64 * p) * G3;
#pragma unroll
        for (int k = 0; k < 32; ++k) {
            wr[k] = pack_h2(Wb[(2*k) * G3 + j],       Wb[(2*k+1) * G3 + j]);
            wz[k] = pack_h2(Wb[(2*k) * G3 + 128 + j], Wb[(2*k+1) * G3 + 128 + j]);
            wn[k] = pack_h2(Wb[(2*k) * G3 + 256 + j], Wb[(2*k+1) * G3 + 256 + j]);
        }
#pragma unroll
        for (int k = 0; k < 32; ++k) { PINU(wr[k]); PINU(wz[k]); PINU(wn[k]); }
    }
    float bn = b_hh[256 + j];
    PINU(bn);

    // ---- producer B-frags (shared by both seqs) + folded biases ----
    f16x8 Bx[3][2][2];
    float pbias[3][2];
#pragma unroll
    for (int g = 0; g < 3; ++g)
#pragma unroll
        for (int e = 0; e < 2; ++e) {
            const int gc = g * 128 + 32 * w + 16 * e + lm;
            pbias[g][e] = b_ih[gc] + ((g < 2) ? b_hh[gc] : 0.f);
#pragma unroll
            for (int kt = 0; kt < 2; ++kt) {
                f16x8 f;
#pragma unroll
                for (int i = 0; i < 8; ++i)
                    f[i] = (_Float16)W_ih[(kt * 32 + lg * 8 + i) * G3 + gc];
                Bx[g][e][kt] = f;
            }
        }

    const unsigned int* __restrict__ xbase = xh + (size_t)b * L_SEQ * XW32;
    const unsigned int* __restrict__ zrow  = xh + (size_t)XTOT;
    const int len = lengths[b];

    uint4 AxF0, AxF1, AxR0, AxR1;
    auto loadA = [&](bool rev, int rowBase, uint4& A0, uint4& A1) {
        const int row = rowBase + lm;
        const int src = rev ? (len - 1 - row) : row;
        const unsigned int* ptr = ((unsigned)src < (unsigned)L_SEQ)
                                ? (xbase + (size_t)src * XW32) : zrow;
        A0 = *(const uint4*)(ptr + lg * 4);
        A1 = *(const uint4*)(ptr + 16 + lg * 4);
    };
    auto produce = [&](int seq, int s0, uint4 P0, uint4 P1) {  // 16-aligned s0
        const f16x8 A0 = __builtin_bit_cast(f16x8, P0);
        const f16x8 A1 = __builtin_bit_cast(f16x8, P1);
#pragma unroll
        for (int g = 0; g < 3; ++g)
#pragma unroll
            for (int e = 0; e < 2; ++e) {
                f32x4 acc = {pbias[g][e], pbias[g][e], pbias[g][e], pbias[g][e]};
                acc = MFMA16(A0, Bx[g][e][0], acc);
                acc = MFMA16(A1, Bx[g][e][1], acc);
                const int colw = 32 * w + 16 * e + lm;
#pragma unroll
                for (int q = 0; q < 4; ++q)
                    ring[seq][s0 + lg * 4 + q][colw * RCOL + g] = acc[q];
            }
    };

    // ---- prologue: fwd [0,16), rev [0,16); AxF holds rows [16,32) ----
    loadA(false, 0, AxF0, AxF1);  produce(0, 0, AxF0, AxF1);
    loadA(true,  0, AxR0, AxR1);  produce(1, 0, AxR0, AxR1);
    loadA(false, 16, AxF0, AxF1);

    float hF = 0.f, hR = 0.f;
    if (tid < 64) { hbufu[0][0][tid] = 0u; hbufu[1][0][tid] = 0u; }
    __syncthreads();

    // t=0 xw values (slot 0)
    float crF = ring[0][0][j * RCOL + 0], czF = ring[0][0][j * RCOL + 1],
          cnF = ring[0][0][j * RCOL + 2];
    float crR = ring[1][0][j * RCOL + 0], czR = ring[1][0][j * RCOL + 1],
          cnR = ring[1][0][j * RCOL + 2];

    float* op = out + (size_t)b * L_SEQ * 256;
    int cur = 0;

    for (int t = 0; t < L_SEQ; ++t) {
        // staggered production on the matrix pipe
        const int ph = t & 15;
        if (ph == 0) {
            produce(0, (t + 16) & (RSLOT - 1), AxF0, AxF1);  // fwd [t+16,t+32)
            loadA(true, t + 16, AxR0, AxR1);                 // for t+8
        } else if (ph == 8) {
            produce(1, (t + 8) & (RSLOT - 1), AxR0, AxR1);   // rev [t+8,t+24)
            loadA(false, t + 24, AxF0, AxF1);                // for t+8 (fwd)
        }

        // prefetch next step's xw (one b96-class read per seq)
        const int sl = (t + 1) & (RSLOT - 1);
        const float nrF = ring[0][sl][j * RCOL + 0];
        const float nzF = ring[0][sl][j * RCOL + 1];
        const float nnF = ring[0][sl][j * RCOL + 2];
        const float nrR = ring[1][sl][j * RCOL + 0];
        const float nzR = ring[1][sl][j * RCOL + 1];
        const float nnR = ring[1][sl][j * RCOL + 2];

        // two independent 96-dot2 chains (fwd + rev) — scheduler interleaves
        float arF = 0.f, azF = 0.f, anF = 0.f;
        float arR = 0.f, azR = 0.f, anR = 0.f;
        const uint4* hbF = (const uint4*)&hbufu[0][cur][p * 32];
        const uint4* hbR = (const uint4*)&hbufu[1][cur][p * 32];
#pragma unroll
        for (int i = 0; i < 8; ++i) {
            const uint4 hv = hbF[i];
            arF = fdot2u(hv.x, wr[4*i+0], arF); arF = fdot2u(hv.y, wr[4*i+1], arF);
            arF = fdot2u(hv.z, wr[4*i+2], arF); arF = fdot2u(hv.w, wr[4*i+3], arF);
            azF = fdot2u(hv.x, wz[4*i+0], azF); azF = fdot2u(hv.y, wz[4*i+1], azF);
            azF = fdot2u(hv.z, wz[4*i+2], azF); azF = fdot2u(hv.w, wz[4*i+3], azF);
            anF = fdot2u(hv.x, wn[4*i+0], anF); anF = fdot2u(hv.y, wn[4*i+1], anF);
            anF = fdot2u(hv.z, wn[4*i+2], anF); anF = fdot2u(hv.w, wn[4*i+3], anF);
        }
#pragma unroll
        for (int i = 0; i < 8; ++i) {
            const uint4 hv = hbR[i];
            arR = fdot2u(hv.x, wr[4*i+0], arR); arR = fdot2u(hv.y, wr[4*i+1], arR);
            arR = fdot2u(hv.z, wr[4*i+2], arR); arR = fdot2u(hv.w, wr[4*i+3], arR);
            azR = fdot2u(hv.x, wz[4*i+0], azR); azR = fdot2u(hv.y, wz[4*i+1], azR);
            azR = fdot2u(hv.z, wz[4*i+2], azR); azR = fdot2u(hv.w, wz[4*i+3], azR);
            anR = fdot2u(hv.x, wn[4*i+0], anR); anR = fdot2u(hv.y, wn[4*i+1], anR);
            anR = fdot2u(hv.z, wn[4*i+2], anR); anR = fdot2u(hv.w, wn[4*i+3], anR);
        }
        arF = qadd1(arF); azF = qadd1(azF); anF = qadd1(anF);
        arR = qadd1(arR); azR = qadd1(azR); anR = qadd1(anR);

        const float rF = fast_sigmoid(crF + arF);
        const float zF = fast_sigmoid(czF + azF);
        const float nF = fast_tanh(cnF + rF * (anF + bn));
        const float hFn = zF * (hF - nF) + nF;
        hF = hFn;
        const float rR = fast_sigmoid(crR + arR);
        const float zR = fast_sigmoid(czR + azR);
        const float nR = fast_tanh(cnR + rR * (anR + bn));
        const float hRn = zR * (hR - nR) + nR;
        hR = hRn;

        if (p == 0) {
            ((_Float16*)&hbufu[0][cur ^ 1][0])[j] = (_Float16)hFn;
            ((_Float16*)&hbufu[1][cur ^ 1][0])[j] = (_Float16)hRn;
            float* o = op + (size_t)t * 256;
            o[j]        = hFn;
            o[128 + j]  = hRn;
        }
        STEP_BARRIER();
        cur ^= 1;
        crF = nrF; czF = nzF; cnF = nnF;
        crR = nrR; czR = nzR; cnR = nnR;
    }
}

// ---------------------------------------------------------------------------
extern "C" void kernel_launch(void* const* d_in, const int* in_sizes, int n_in,
                              void* d_out, int out_size, void* d_ws, size_t ws_size,
                              hipStream_t stream) {
    const float* x       = (const float*)d_in[0];
    const int*   lengths = (const int*)  d_in[1];
    const float* W_ih    = (const float*)d_in[2];
    const float* W_hh    = (const float*)d_in[3];
    const float* b_ih    = (const float*)d_in[4];
    const float* b_hh    = (const float*)d_in[5];
    float* out = (float*)d_out;

    unsigned int* xh = (unsigned int*)d_ws;      // (XTOT + XW32) u32 = 8.4 MB

    pack_x_kernel<<<dim3((XTOT + 255) / 256), dim3(256), 0, stream>>>(x, xh);
    bigru_dual<<<dim3(NSEQ), dim3(256), 0, stream>>>(
        xh, lengths, W_ih, W_hh, b_ih, b_hh, out);
}

// Round 17
// 1292.852 us; speedup vs baseline: 1.2592x; 1.2592x over previous
//
#include <hip/hip_runtime.h>

#define L_SEQ 2048
#define C_IN  64
#define HH    128
#define NSEQ  32
#define B2    64
#define G3    384
#define XW32  (C_IN / 2)                 // 32 u32 per packed x row
#define XTOT  (NSEQ * L_SEQ * XW32)
#define RSLOT 48                         // ring: 3 windows x 16 steps
#define RG    130                        // ring col stride (128 + 2 pad)

typedef _Float16 f16x8 __attribute__((ext_vector_type(8)));
typedef float    f32x4 __attribute__((ext_vector_type(4)));
typedef _Float16 half2_t __attribute__((ext_vector_type(2)));

#define PINU(v) asm volatile("" : "+v"(v))
// per-step barrier: drain LDS only; vmcnt (out stores, x loads) floats
#define STEP_BARRIER() asm volatile("s_waitcnt lgkmcnt(0)\n\ts_barrier" ::: "memory")
#define MFMA16(a, b, c) __builtin_amdgcn_mfma_f32_16x16x32_f16((a), (b), (c), 0, 0, 0)

__device__ __forceinline__ float fdot2u(unsigned int a, unsigned int b, float c) {
    return __builtin_amdgcn_fdot2(__builtin_bit_cast(half2_t, a),
                                  __builtin_bit_cast(half2_t, b), c, false);
}
__device__ __forceinline__ unsigned int pack_h2(float a, float b) {
    half2_t t; t.x = (_Float16)a; t.y = (_Float16)b;
    return __builtin_bit_cast(unsigned int, t);
}
// quad-perm DPP add: reduce across lane^1, pure VALU (no DS pipe)
__device__ __forceinline__ float qadd1(float x) {
    int t = __builtin_amdgcn_update_dpp(0, __builtin_bit_cast(int, x),
                                        0xB1, 0xF, 0xF, true); // [1,0,3,2]
    return x + __builtin_bit_cast(float, t);
}
__device__ __forceinline__ float fast_sigmoid(float x) {
    float e = __builtin_amdgcn_exp2f(-1.4426950408889634f * x);
    return __builtin_amdgcn_rcpf(1.0f + e);
}
__device__ __forceinline__ float fast_tanh(float x) {
    float a = fabsf(x);
    float e = __builtin_amdgcn_exp2f(-2.8853900817779268f * a);  // e^{-2a}
    float r = (1.0f - e) * __builtin_amdgcn_rcpf(1.0f + e);
    return copysignf(r, x);
}

// ---------------------------------------------------------------------------
__global__ __launch_bounds__(256)
void pack_x_kernel(const float* __restrict__ x, unsigned int* __restrict__ xh)
{
    const size_t i = (size_t)blockIdx.x * 256 + threadIdx.x;
    if (i < (size_t)XTOT) {
        const float2 v = ((const float2*)x)[i];
        xh[i] = pack_h2(v.x, v.y);
    }
    if (i < XW32) xh[(size_t)XTOT + i] = 0u;     // zero row for ragged tail
}

// ---------------------------------------------------------------------------
// Fused BiGRU (r15 structure + STAGGERED fine-grained production).
// 64 blocks x 256 threads (4 waves), one sequence per block.
// Recurrence: identical to r15 (best-measured core): 96 pinned packed-f16
//   W_hh u32/thread, 96 dot2/step (2 accumulators per gate), DPP qadd1,
//   h f16 double-buffered in 512 B LDS, one lgkm-only barrier/step.
// X-projection: per wave, 6 units per 16 steps; unit = 2 MFMA + 4 ring
//   writes (~60 cyc). Wave w runs unit u at (t-4w)&15 == u, loadA at ==6.
//   => at most ~2 units per block-step, on DIFFERENT waves — no all-wave
//   burst, so the per-step barrier no longer drains a 24-write burst.
//   Ring = 48 slots (3 windows); units for window [B+32,B+48) all complete
//   by t=B+17, first read at t=B+31 — 14+ steps of slack, WAR-free.
// ---------------------------------------------------------------------------
__global__ __launch_bounds__(256) __attribute__((amdgpu_waves_per_eu(1, 1)))
void bigru_fused(const unsigned int* __restrict__ xh,
                 const int* __restrict__ lengths,
                 const float* __restrict__ W_ih, const float* __restrict__ W_hh,
                 const float* __restrict__ b_ih, const float* __restrict__ b_hh,
                 float* __restrict__ out)
{
    __shared__ unsigned int hbufu[2][64];        // h as f16 pairs, dbuf
    __shared__ float ring[RSLOT][3][RG];         // xw ring, ~74.9 KB

    const int tid = threadIdx.x;
    const int s   = blockIdx.x;
    const bool fwd = (s < NSEQ);
    const int  len = fwd ? L_SEQ : lengths[s - NSEQ];
    const unsigned int* __restrict__ xbase = xh + (size_t)(s % NSEQ) * L_SEQ * XW32;
    const unsigned int* __restrict__ zrow  = xh + (size_t)XTOT;

    const int j = tid >> 1;          // col 0..127
    const int p = tid & 1;           // K half
    const int w  = tid >> 6;         // wave 0..3 -> gate cols [32w, 32w+32)
    const int l  = tid & 63;
    const int lm = l & 15;
    const int lg = l >> 4;

    // ---- recurrence weights: 96 packed f16-pair u32, pinned ----
    unsigned int wr[32], wz[32], wn[32];
    {
        const float* Wb = W_hh + (size_t)(64 * p) * G3;
#pragma unroll
        for (int k = 0; k < 32; ++k) {
            wr[k] = pack_h2(Wb[(2*k) * G3 + j],       Wb[(2*k+1) * G3 + j]);
            wz[k] = pack_h2(Wb[(2*k) * G3 + 128 + j], Wb[(2*k+1) * G3 + 128 + j]);
            wn[k] = pack_h2(Wb[(2*k) * G3 + 256 + j], Wb[(2*k+1) * G3 + 256 + j]);
        }
#pragma unroll
        for (int k = 0; k < 32; ++k) { PINU(wr[k]); PINU(wz[k]); PINU(wn[k]); }
    }
    float bn = b_hh[256 + j];
    PINU(bn);

    // ---- producer B-frags (W_ih) + folded biases ----
    f16x8 Bx[3][2][2];               // [gate][e-tile][kt] (compile-time indexed)
    float pbias[3][2];
#pragma unroll
    for (int g = 0; g < 3; ++g)
#pragma unroll
        for (int e = 0; e < 2; ++e) {
            const int gc = g * 128 + 32 * w + 16 * e + lm;
            pbias[g][e] = b_ih[gc] + ((g < 2) ? b_hh[gc] : 0.f);
#pragma unroll
            for (int kt = 0; kt < 2; ++kt) {
                f16x8 f;
#pragma unroll
                for (int i = 0; i < 8; ++i)
                    f[i] = (_Float16)W_ih[(kt * 32 + lg * 8 + i) * G3 + gc];
                Bx[g][e][kt] = f;
            }
        }

    uint4 AxP0, AxP1;                // x A-frags for the window being produced
    auto loadA = [&](int rowBase) {
        const int row = rowBase + lm;
        const int src = fwd ? row : (len - 1 - row);
        const unsigned int* ptr = ((unsigned)src < (unsigned)L_SEQ)
                                ? (xbase + (size_t)src * XW32) : zrow;
        AxP0 = *(const uint4*)(ptr + lg * 4);
        AxP1 = *(const uint4*)(ptr + 16 + lg * 4);
    };

    // one (gate, col-tile) production unit: 2 MFMA + 4 ring writes
#define UNIT(G, E) do {                                                        \
        f32x4 acc = {pbias[G][E], pbias[G][E], pbias[G][E], pbias[G][E]};      \
        acc = MFMA16(Af0, Bx[G][E][0], acc);                                   \
        acc = MFMA16(Af1, Bx[G][E][1], acc);                                   \
        const int colw = 32 * w + 16 * (E) + lm;                               \
        ring[s0 + lg * 4 + 0][G][colw] = acc[0];                               \
        ring[s0 + lg * 4 + 1][G][colw] = acc[1];                               \
        ring[s0 + lg * 4 + 2][G][colw] = acc[2];                               \
        ring[s0 + lg * 4 + 3][G][colw] = acc[3];                               \
    } while (0)

    auto produce_unit = [&](int s0, int u) {
        const f16x8 Af0 = __builtin_bit_cast(f16x8, AxP0);
        const f16x8 Af1 = __builtin_bit_cast(f16x8, AxP1);
        if      (u == 0) UNIT(0, 0);
        else if (u == 1) UNIT(0, 1);
        else if (u == 2) UNIT(1, 0);
        else if (u == 3) UNIT(1, 1);
        else if (u == 4) UNIT(2, 0);
        else             UNIT(2, 1);
    };

    // ---- h init ----
    float hreg = 0.f;
    if (tid < 64) hbufu[0][tid] = 0u;

    // ---- prologue: windows 0,1 produced in full; AxP <- rows [32,48) ----
    loadA(0);
#pragma unroll
    for (int u = 0; u < 6; ++u) produce_unit(0, u);
    loadA(16);
#pragma unroll
    for (int u = 0; u < 6; ++u) produce_unit(16, u);
    loadA(32);
    __syncthreads();

    float cr = ring[0][0][j], cz = ring[0][1][j], cn = ring[0][2][j];

    float* outbase = out + (size_t)(s % NSEQ) * L_SEQ * 256 + (fwd ? 0 : HH);
    int cur = 0;
    int slotN = 1;                   // ring slot of step t+1

    for (int t = 0; t < L_SEQ; ++t) {
        // staggered production: wave w does unit q at (t-4w)&15==q (q<6),
        // refills its A-frags at q==6. Wave-uniform scalar branches.
        {
            const int q = (t - 4 * w) & 15;
            if (q < 6) {
                const int base16 = t - q - 4 * w;        // wave-local 16-group
                if (base16 >= 0 && base16 + 32 < L_SEQ) {
                    const int S = (base16 + 32) % RSLOT;
                    produce_unit(S, q);
                }
            } else if (q == 6) {
                const int rowBase = t - 6 - 4 * w + 48;  // next window's rows
                if (rowBase < L_SEQ) loadA(rowBase);
            }
        }

        // prefetch next step's xw from the ring (LDS, short latency)
        const float nr = ring[slotN][0][j];
        const float nz = ring[slotN][1][j];
        const float nn = ring[slotN][2][j];
        ++slotN; if (slotN == RSLOT) slotN = 0;

        // 96 dot2 on the VALU pipe; 2 accumulators/gate halve the dep chain
        float arA = 0.f, azA = 0.f, anA = 0.f;
        float arB = 0.f, azB = 0.f, anB = 0.f;
        const uint4* hb = (const uint4*)&hbufu[cur][p * 32];
#pragma unroll
        for (int i = 0; i < 4; ++i) {
            const uint4 hv = hb[i];
            arA = fdot2u(hv.x, wr[4*i+0], arA); arA = fdot2u(hv.y, wr[4*i+1], arA);
            arA = fdot2u(hv.z, wr[4*i+2], arA); arA = fdot2u(hv.w, wr[4*i+3], arA);
            azA = fdot2u(hv.x, wz[4*i+0], azA); azA = fdot2u(hv.y, wz[4*i+1], azA);
            azA = fdot2u(hv.z, wz[4*i+2], azA); azA = fdot2u(hv.w, wz[4*i+3], azA);
            anA = fdot2u(hv.x, wn[4*i+0], anA); anA = fdot2u(hv.y, wn[4*i+1], anA);
            anA = fdot2u(hv.z, wn[4*i+2], anA); anA = fdot2u(hv.w, wn[4*i+3], anA);
        }
#pragma unroll
        for (int i = 4; i < 8; ++i) {
            const uint4 hv = hb[i];
            arB = fdot2u(hv.x, wr[4*i+0], arB); arB = fdot2u(hv.y, wr[4*i+1], arB);
            arB = fdot2u(hv.z, wr[4*i+2], arB); arB = fdot2u(hv.w, wr[4*i+3], arB);
            azB = fdot2u(hv.x, wz[4*i+0], azB); azB = fdot2u(hv.y, wz[4*i+1], azB);
            azB = fdot2u(hv.z, wz[4*i+2], azB); azB = fdot2u(hv.w, wz[4*i+3], azB);
            anB = fdot2u(hv.x, wn[4*i+0], anB); anB = fdot2u(hv.y, wn[4*i+1], anB);
            anB = fdot2u(hv.z, wn[4*i+2], anB); anB = fdot2u(hv.w, wn[4*i+3], anB);
        }
        float ar = arA + arB, az = azA + azB, an = anA + anB;
        ar = qadd1(ar); az = qadd1(az); an = qadd1(an);

        const float r = fast_sigmoid(cr + ar);
        const float z = fast_sigmoid(cz + az);
        const float n = fast_tanh(cn + r * (an + bn));
        const float hnew = z * (hreg - n) + n;
        hreg = hnew;

        if (p == 0) {
            ((_Float16*)&hbufu[cur ^ 1][0])[j] = (_Float16)hnew;
            outbase[(size_t)t * 256 + j] = hnew;
        }
        STEP_BARRIER();
        cur ^= 1;
        cr = nr; cz = nz; cn = nn;
    }
#undef UNIT
}

// ---------------------------------------------------------------------------
extern "C" void kernel_launch(void* const* d_in, const int* in_sizes, int n_in,
                              void* d_out, int out_size, void* d_ws, size_t ws_size,
                              hipStream_t stream) {
    const float* x       = (const float*)d_in[0];
    const int*   lengths = (const int*)  d_in[1];
    const float* W_ih    = (const float*)d_in[2];
    const float* W_hh    = (const float*)d_in[3];
    const float* b_ih    = (const float*)d_in[4];
    const float* b_hh    = (const float*)d_in[5];
    float* out = (float*)d_out;

    unsigned int* xh = (unsigned int*)d_ws;      // (XTOT + XW32) u32 = 8.4 MB

    pack_x_kernel<<<dim3((XTOT + 255) / 256), dim3(256), 0, stream>>>(x, xh);
    bigru_fused<<<dim3(B2), dim3(256), 0, stream>>>(
        xh, lengths, W_ih, W_hh, b_ih, b_hh, out);
}

// Round 18
// 947.109 us; speedup vs baseline: 1.7188x; 1.3650x over previous
//
#include <hip/hip_runtime.h>

#define L_SEQ 2048
#define C_IN  64
#define HH    128
#define NSEQ  32
#define B2    64
#define G3    384
#define XW32  (C_IN / 2)                 // 32 u32 per packed x row
#define XTOT  (NSEQ * L_SEQ * XW32)
#define RSLOT 48                         // ring: 3 windows x 16 steps
#define RG    130                        // ring col stride (128 + 2 pad)

typedef _Float16 f16x8 __attribute__((ext_vector_type(8)));
typedef float    f32x4 __attribute__((ext_vector_type(4)));
typedef _Float16 half2_t __attribute__((ext_vector_type(2)));

#define PINU(v) asm volatile("" : "+v"(v))
// per-step barrier: drain LDS only; vmcnt (out stores, x loads) floats
#define STEP_BARRIER() asm volatile("s_waitcnt lgkmcnt(0)\n\ts_barrier" ::: "memory")
#define MFMA16(a, b, c) __builtin_amdgcn_mfma_f32_16x16x32_f16((a), (b), (c), 0, 0, 0)

__device__ __forceinline__ float fdot2u(unsigned int a, unsigned int b, float c) {
    return __builtin_amdgcn_fdot2(__builtin_bit_cast(half2_t, a),
                                  __builtin_bit_cast(half2_t, b), c, false);
}
__device__ __forceinline__ unsigned int pack_h2(float a, float b) {
    half2_t t; t.x = (_Float16)a; t.y = (_Float16)b;
    return __builtin_bit_cast(unsigned int, t);
}
// quad-perm DPP add: reduce across lane^1, pure VALU (no DS pipe)
__device__ __forceinline__ float qadd1(float x) {
    int t = __builtin_amdgcn_update_dpp(0, __builtin_bit_cast(int, x),
                                        0xB1, 0xF, 0xF, true); // [1,0,3,2]
    return x + __builtin_bit_cast(float, t);
}
__device__ __forceinline__ float fast_sigmoid(float x) {
    float e = __builtin_amdgcn_exp2f(-1.4426950408889634f * x);
    return __builtin_amdgcn_rcpf(1.0f + e);
}
__device__ __forceinline__ float fast_tanh(float x) {
    float a = fabsf(x);
    float e = __builtin_amdgcn_exp2f(-2.8853900817779268f * a);  // e^{-2a}
    float r = (1.0f - e) * __builtin_amdgcn_rcpf(1.0f + e);
    return copysignf(r, x);
}

// ---------------------------------------------------------------------------
// Pre-pass: pack x (f32) -> f16-pair rows in ws, plus one zero row at the end.
// ---------------------------------------------------------------------------
__global__ __launch_bounds__(256)
void pack_x_kernel(const float* __restrict__ x, unsigned int* __restrict__ xh)
{
    const size_t i = (size_t)blockIdx.x * 256 + threadIdx.x;
    if (i < (size_t)XTOT) {
        const float2 v = ((const float2*)x)[i];
        xh[i] = pack_h2(v.x, v.y);
    }
    if (i < XW32) xh[(size_t)XTOT + i] = 0u;     // zero row for ragged tail
}

// ---------------------------------------------------------------------------
// Fused BiGRU: 64 blocks x 256 threads (4 waves), ONE sequence per block.
// RECURRENCE (VALU pipe, r7's proven core): thread = (col j = tid>>1,
//   K-half p = tid&1); 96 packed f16-pair W_hh u32 pinned in VGPRs;
//   96 v_dot2 per step (2 accumulators per gate to halve the dep chain);
//   one DPP qadd1 per gate; h f16 double-buffered in 512 B LDS.
// X-PROJECTION (matrix pipe): time-batched M=16 MFMA — every 16 steps each
//   wave computes xw for 16 future timesteps (its 96 gate-cols) with 12
//   mfma_f32_16x16x32_f16 (A rows = timesteps: NO M-waste) into a 48-slot
//   LDS ring (3 windows; writes [t+24,t+40) never alias live reads [t,t+24)).
//   x A-frags are per-lane rows from the packed-f16 buffer, loaded one
//   window (16 steps) ahead. The MFMAs run on the matrix pipe while the
//   same wave's dot2s occupy the VALU -> dual-pipe overlap, ~0.75 MFMA/step.
// One lgkm-only barrier per step; out-stores and x loads float on vmcnt.
// This is the best-measured configuration (r15: 943 us); rounds 16-17's
// structural variants (dual-seq ILP, staggered production) both regressed
// and were reverted.
// ---------------------------------------------------------------------------
__global__ __launch_bounds__(256) __attribute__((amdgpu_waves_per_eu(1, 1)))
void bigru_fused(const unsigned int* __restrict__ xh,
                 const int* __restrict__ lengths,
                 const float* __restrict__ W_ih, const float* __restrict__ W_hh,
                 const float* __restrict__ b_ih, const float* __restrict__ b_hh,
                 float* __restrict__ out)
{
    __shared__ unsigned int hbufu[2][64];        // h as f16 pairs, dbuf
    __shared__ float ring[RSLOT][3][RG];         // xw ring, ~74.9 KB

    const int tid = threadIdx.x;
    const int s   = blockIdx.x;
    const bool fwd = (s < NSEQ);
    const int  len = fwd ? L_SEQ : lengths[s - NSEQ];
    const unsigned int* __restrict__ xbase = xh + (size_t)(s % NSEQ) * L_SEQ * XW32;
    const unsigned int* __restrict__ zrow  = xh + (size_t)XTOT;

    // consumer (recurrence) identity
    const int j = tid >> 1;          // col 0..127
    const int p = tid & 1;           // K half
    // producer (MFMA) identity
    const int w  = tid >> 6;         // wave 0..3 -> gate cols [32w, 32w+32)
    const int l  = tid & 63;
    const int lm = l & 15;
    const int lg = l >> 4;

    // ---- recurrence weights: 96 packed f16-pair u32, pinned ----
    unsigned int wr[32], wz[32], wn[32];
    {
        const float* Wb = W_hh + (size_t)(64 * p) * G3;
#pragma unroll
        for (int k = 0; k < 32; ++k) {
            wr[k] = pack_h2(Wb[(2*k) * G3 + j],       Wb[(2*k+1) * G3 + j]);
            wz[k] = pack_h2(Wb[(2*k) * G3 + 128 + j], Wb[(2*k+1) * G3 + 128 + j]);
            wn[k] = pack_h2(Wb[(2*k) * G3 + 256 + j], Wb[(2*k+1) * G3 + 256 + j]);
        }
#pragma unroll
        for (int k = 0; k < 32; ++k) { PINU(wr[k]); PINU(wz[k]); PINU(wn[k]); }
    }
    float bn = b_hh[256 + j];
    PINU(bn);

    // ---- producer B-frags (W_ih) + folded biases ----
    f16x8 Bx[3][2][2];               // [gate][e-tile][kt]
    float pbias[3][2];
#pragma unroll
    for (int g = 0; g < 3; ++g)
#pragma unroll
        for (int e = 0; e < 2; ++e) {
            const int gc = g * 128 + 32 * w + 16 * e + lm;
            pbias[g][e] = b_ih[gc] + ((g < 2) ? b_hh[gc] : 0.f);
#pragma unroll
            for (int kt = 0; kt < 2; ++kt) {
                f16x8 f;
#pragma unroll
                for (int i = 0; i < 8; ++i)
                    f[i] = (_Float16)W_ih[(kt * 32 + lg * 8 + i) * G3 + gc];
                Bx[g][e][kt] = f;
            }
        }

    // ---- producer helpers ----
    uint4 AxP0, AxP1;                // x A-frags for the NEXT window
    auto loadA = [&](int rowBase) {
        const int row = rowBase + lm;
        const int src = fwd ? row : (len - 1 - row);
        const unsigned int* ptr = ((unsigned)src < (unsigned)L_SEQ)
                                ? (xbase + (size_t)src * XW32) : zrow;
        AxP0 = *(const uint4*)(ptr + lg * 4);
        AxP1 = *(const uint4*)(ptr + 16 + lg * 4);
    };
    auto produce = [&](int s0) {     // writes slots [s0, s0+16)
        const f16x8 A0 = __builtin_bit_cast(f16x8, AxP0);
        const f16x8 A1 = __builtin_bit_cast(f16x8, AxP1);
#pragma unroll
        for (int g = 0; g < 3; ++g)
#pragma unroll
            for (int e = 0; e < 2; ++e) {
                f32x4 acc = {pbias[g][e], pbias[g][e], pbias[g][e], pbias[g][e]};
                acc = MFMA16(A0, Bx[g][e][0], acc);
                acc = MFMA16(A1, Bx[g][e][1], acc);
                const int colw = 32 * w + 16 * e + lm;
#pragma unroll
                for (int q = 0; q < 4; ++q)
                    ring[s0 + lg * 4 + q][g][colw] = acc[q];
            }
    };

    // ---- h init ----
    float hreg = 0.f;
    if (tid < 64) hbufu[0][tid] = 0u;

    // ---- prologue: windows 0,1 produced; window 2 loads in flight ----
    loadA(0);  produce(0);
    loadA(16); produce(16);
    loadA(32);
    __syncthreads();

    float cr = ring[0][0][j], cz = ring[0][1][j], cn = ring[0][2][j];

    float* outbase = out + (size_t)(s % NSEQ) * L_SEQ * 256 + (fwd ? 0 : HH);
    int cur = 0;
    int slotN = 1;                   // ring slot of step t+1
    int s0 = 32;                     // slot base of next production

    for (int t = 0; t < L_SEQ; ++t) {
        // mid-window: produce rows [t+24, t+40) on the MATRIX pipe, then
        // issue next window's x loads (16 steps of latency cover)
        if ((t & 15) == 8) {
            if (t + 24 < L_SEQ) produce(s0);
            s0 += 16; if (s0 >= RSLOT) s0 -= RSLOT;
            if (t + 40 < L_SEQ) loadA(t + 40);
        }

        // prefetch next step's xw from the ring (LDS, short latency)
        const float nr = ring[slotN][0][j];
        const float nz = ring[slotN][1][j];
        const float nn = ring[slotN][2][j];
        ++slotN; if (slotN == RSLOT) slotN = 0;

        // 96 dot2 on the VALU pipe; 2 accumulators/gate halve the dep chain
        float arA = 0.f, azA = 0.f, anA = 0.f;
        float arB = 0.f, azB = 0.f, anB = 0.f;
        const uint4* hb = (const uint4*)&hbufu[cur][p * 32];
#pragma unroll
        for (int i = 0; i < 4; ++i) {
            const uint4 hv = hb[i];
            arA = fdot2u(hv.x, wr[4*i+0], arA); arA = fdot2u(hv.y, wr[4*i+1], arA);
            arA = fdot2u(hv.z, wr[4*i+2], arA); arA = fdot2u(hv.w, wr[4*i+3], arA);
            azA = fdot2u(hv.x, wz[4*i+0], azA); azA = fdot2u(hv.y, wz[4*i+1], azA);
            azA = fdot2u(hv.z, wz[4*i+2], azA); azA = fdot2u(hv.w, wz[4*i+3], azA);
            anA = fdot2u(hv.x, wn[4*i+0], anA); anA = fdot2u(hv.y, wn[4*i+1], anA);
            anA = fdot2u(hv.z, wn[4*i+2], anA); anA = fdot2u(hv.w, wn[4*i+3], anA);
        }
#pragma unroll
        for (int i = 4; i < 8; ++i) {
            const uint4 hv = hb[i];
            arB = fdot2u(hv.x, wr[4*i+0], arB); arB = fdot2u(hv.y, wr[4*i+1], arB);
            arB = fdot2u(hv.z, wr[4*i+2], arB); arB = fdot2u(hv.w, wr[4*i+3], arB);
            azB = fdot2u(hv.x, wz[4*i+0], azB); azB = fdot2u(hv.y, wz[4*i+1], azB);
            azB = fdot2u(hv.z, wz[4*i+2], azB); azB = fdot2u(hv.w, wz[4*i+3], azB);
            anB = fdot2u(hv.x, wn[4*i+0], anB); anB = fdot2u(hv.y, wn[4*i+1], anB);
            anB = fdot2u(hv.z, wn[4*i+2], anB); anB = fdot2u(hv.w, wn[4*i+3], anB);
        }
        float ar = arA + arB, az = azA + azB, an = anA + anB;
        ar = qadd1(ar); az = qadd1(az); an = qadd1(an);

        const float r = fast_sigmoid(cr + ar);
        const float z = fast_sigmoid(cz + az);
        const float n = fast_tanh(cn + r * (an + bn));
        const float hnew = z * (hreg - n) + n;
        hreg = hnew;

        if (p == 0) {
            ((_Float16*)&hbufu[cur ^ 1][0])[j] = (_Float16)hnew;
            outbase[(size_t)t * 256 + j] = hnew;
        }
        STEP_BARRIER();
        cur ^= 1;
        cr = nr; cz = nz; cn = nn;
    }
}

// ---------------------------------------------------------------------------
extern "C" void kernel_launch(void* const* d_in, const int* in_sizes, int n_in,
                              void* d_out, int out_size, void* d_ws, size_t ws_size,
                              hipStream_t stream) {
    const float* x       = (const float*)d_in[0];
    const int*   lengths = (const int*)  d_in[1];
    const float* W_ih    = (const float*)d_in[2];
    const float* W_hh    = (const float*)d_in[3];
    const float* b_ih    = (const float*)d_in[4];
    const float* b_hh    = (const float*)d_in[5];
    float* out = (float*)d_out;

    unsigned int* xh = (unsigned int*)d_ws;      // (XTOT + XW32) u32 = 8.4 MB

    pack_x_kernel<<<dim3((XTOT + 255) / 256), dim3(256), 0, stream>>>(x, xh);
    bigru_fused<<<dim3(B2), dim3(256), 0, stream>>>(
        xh, lengths, W_ih, W_hh, b_ih, b_hh, out);
}